// Round 3
// baseline (852.871 us; speedup 1.0000x reference)
//
#include <hip/hip_runtime.h>
#include <cstdint>
#include <cstddef>

#define N_NODES 12000
#define N_EDGES 384000
#define NEG_SLOPE 0.2f
#define NPAD 12032           // 94*128, zero-padded rows for decoder
#define KP 64                // padded K for bf16 MFMA (40 -> 64)

typedef __attribute__((ext_vector_type(8))) short bf16x8;
typedef __attribute__((ext_vector_type(4))) float f32x4;

__device__ __forceinline__ float leaky(float v) { return v > 0.f ? v : NEG_SLOPE * v; }

// ---------------------------------------------------------------------------
// h = x @ W  (per-node row), plus alpha_src = h.a_src, alpha_dst = h.a_dst
// ---------------------------------------------------------------------------
template <int FIN, int FOUT>
__global__ __launch_bounds__(256) void node_linear(
    const float* __restrict__ x, const float* __restrict__ W,
    const float* __restrict__ a_src, const float* __restrict__ a_dst,
    float* __restrict__ h, float* __restrict__ as_, float* __restrict__ ad_) {
  __shared__ float Ws[FIN * FOUT];
  __shared__ float av[FOUT], dv[FOUT];
  for (int i = threadIdx.x; i < FIN * FOUT; i += blockDim.x) Ws[i] = W[i];
  if (threadIdx.x < FOUT) {
    av[threadIdx.x] = a_src[threadIdx.x];
    dv[threadIdx.x] = a_dst[threadIdx.x];
  }
  __syncthreads();
  const int node = blockIdx.x * blockDim.x + threadIdx.x;
  if (node >= N_NODES) return;
  float xr[FIN];
#pragma unroll
  for (int k = 0; k < FIN; ++k) xr[k] = x[node * FIN + k];
  float ssum = 0.f, dsum = 0.f;
#pragma unroll 1
  for (int c = 0; c < FOUT; ++c) {
    float acc = 0.f;
#pragma unroll
    for (int k = 0; k < FIN; ++k) acc += xr[k] * Ws[k * FOUT + c];
    h[node * FOUT + c] = acc;
    ssum += acc * av[c];
    dsum += acc * dv[c];
  }
  as_[node] = ssum;
  ad_[node] = dsum;
}

// ---------------------------------------------------------------------------
// CSR build: histogram of dst (incl. self-loops), exclusive scan, scatter src
// ---------------------------------------------------------------------------
__global__ __launch_bounds__(256) void histo_kernel(const int* __restrict__ dst,
                                                    int* __restrict__ deg) {
  const int i = blockIdx.x * blockDim.x + threadIdx.x;
  if (i >= N_EDGES + N_NODES) return;
  const int d = (i < N_EDGES) ? dst[i] : (i - N_EDGES);
  atomicAdd(&deg[d], 1);
}

__global__ __launch_bounds__(1024) void scan_kernel(const int* __restrict__ deg,
                                                    int* __restrict__ rowp) {
  __shared__ int wsum[16];
  __shared__ int carry_s;
  const int t = threadIdx.x;
  const int lane = t & 63;
  const int w = t >> 6;
  if (t == 0) carry_s = 0;
  __syncthreads();
  for (int base = 0; base < N_NODES; base += 1024) {
    const int idx = base + t;
    const int v = (idx < N_NODES) ? deg[idx] : 0;
    int run = v;
#pragma unroll
    for (int off = 1; off < 64; off <<= 1) {
      const int u = __shfl_up(run, off);
      if (lane >= off) run += u;
    }
    if (lane == 63) wsum[w] = run;
    __syncthreads();
    if (w == 0) {
      int x = (lane < 16) ? wsum[lane] : 0;
#pragma unroll
      for (int off = 1; off < 16; off <<= 1) {
        const int u = __shfl_up(x, off);
        if (lane >= off) x += u;
      }
      if (lane < 16) wsum[lane] = x;
    }
    __syncthreads();
    const int wpre = (w == 0) ? 0 : wsum[w - 1];
    const int c = carry_s;
    if (idx < N_NODES) rowp[idx] = c + wpre + run - v;  // exclusive
    __syncthreads();
    if (t == 1023) carry_s = c + wsum[15];
    __syncthreads();
  }
  if (t == 0) rowp[N_NODES] = carry_s;
}

__global__ __launch_bounds__(256) void scatter_kernel(
    const int* __restrict__ src, const int* __restrict__ dst,
    const int* __restrict__ rowp, int* __restrict__ fill,
    int* __restrict__ esrc) {
  const int i = blockIdx.x * blockDim.x + threadIdx.x;
  if (i >= N_EDGES + N_NODES) return;
  int s, d;
  if (i < N_EDGES) {
    s = src[i];
    d = dst[i];
  } else {
    s = d = i - N_EDGES;
  }
  const int pos = rowp[d] + atomicAdd(&fill[d], 1);
  esrc[pos] = s;
}

// ---------------------------------------------------------------------------
// Per-dst-node segment softmax + aggregation. One wave per node.
// ---------------------------------------------------------------------------
template <int F>
__global__ __launch_bounds__(256) void gat_aggregate(
    const int* __restrict__ rowp, const int* __restrict__ esrc,
    const float* __restrict__ h, const float* __restrict__ as_,
    const float* __restrict__ ad_, const float* __restrict__ b,
    float* __restrict__ out) {
  __shared__ float wc[4][128];
  __shared__ int sc[4][128];
  const int ws = threadIdx.x >> 6;
  const int wid = (blockIdx.x * blockDim.x + threadIdx.x) >> 6;
  const int lane = threadIdx.x & 63;
  if (wid >= N_NODES) return;
  const int start = rowp[wid], end = rowp[wid + 1];
  const float adv = ad_[wid];

  int s0 = 0, s1 = 0;
  float e0 = -1e30f, e1 = -1e30f;
  const int i0 = start + lane, i1 = start + 64 + lane;
  if (i0 < end) { s0 = esrc[i0]; e0 = leaky(as_[s0] + adv); }
  if (i1 < end) { s1 = esrc[i1]; e1 = leaky(as_[s1] + adv); }
  float m = fmaxf(e0, e1);
  for (int i = start + 128 + lane; i < end; i += 64)
    m = fmaxf(m, leaky(as_[esrc[i]] + adv));
#pragma unroll
  for (int off = 32; off; off >>= 1) m = fmaxf(m, __shfl_xor(m, off));

  const float w0 = (i0 < end) ? __expf(e0 - m) : 0.f;
  const float w1 = (i1 < end) ? __expf(e1 - m) : 0.f;
  float ssum = w0 + w1;
  for (int i = start + 128 + lane; i < end; i += 64)
    ssum += __expf(leaky(as_[esrc[i]] + adv) - m);
#pragma unroll
  for (int off = 32; off; off >>= 1) ssum += __shfl_xor(ssum, off);
  const float inv = 1.f / ssum;

  sc[ws][lane] = s0;
  sc[ws][lane + 64] = s1;
  wc[ws][lane] = w0;
  wc[ws][lane + 64] = w1;

  const int deg = end - start;
  const int ncached = deg < 128 ? deg : 128;
  float acc = 0.f, acc2 = 0.f;
  int j = 0;
  for (; j + 1 < ncached; j += 2) {
    const int t0 = sc[ws][j], t1 = sc[ws][j + 1];
    const float u0 = wc[ws][j], u1 = wc[ws][j + 1];
    if (lane < F) {
      acc += u0 * h[t0 * F + lane];
      acc2 += u1 * h[t1 * F + lane];
    }
  }
  for (; j < ncached; ++j)
    if (lane < F) acc += wc[ws][j] * h[sc[ws][j] * F + lane];
  for (int i = start + 128; i < end; ++i) {
    const int s = esrc[i];
    const float w = __expf(leaky(as_[s] + adv) - m);
    if (lane < F) acc += w * h[s * F + lane];
  }
  if (lane < F) {
    const float o = (acc + acc2) * inv + b[lane];
    out[wid * F + lane] = o > 0.f ? o : 0.f;
  }
}

// ---------------------------------------------------------------------------
// Split z (f32 [N][40]) into hi/lo bf16 [NPAD][KP], zero-padded.
// ---------------------------------------------------------------------------
__global__ __launch_bounds__(256) void split_bf16(const float* __restrict__ z,
                                                  short* __restrict__ zh,
                                                  short* __restrict__ zl) {
  const int idx = blockIdx.x * 256 + threadIdx.x;
  if (idx >= NPAD * KP) return;
  const int row = idx >> 6, k = idx & (KP - 1);
  float v = 0.f;
  if (row < N_NODES && k < 40) v = z[row * 40 + k];
  const unsigned u = __float_as_uint(v);
  const unsigned hb = (u + 0x7fffu + ((u >> 16) & 1u)) >> 16;  // RNE
  const float hf = __uint_as_float(hb << 16);
  const float r = v - hf;
  const unsigned ur = __float_as_uint(r);
  const unsigned lb = (ur + 0x7fffu + ((ur >> 16) & 1u)) >> 16;
  zh[idx] = (short)hb;
  zl[idx] = (short)lb;
}

// ---------------------------------------------------------------------------
// Decoder: out = sigmoid(z z^T) via split-bf16 MFMA. Triangular 1-D grid of
// 128x128 tiles; 4 waves/block, each wave: 32 rows x 128 cols (2x8 tiles of
// 16x16x32 MFMA, K=64, 3 products hh/hl/lh). No LDS; z panels are L2-resident.
// C/D layout (m89): lane l, reg j -> row (l>>4)*4+j, col l&15.
// ---------------------------------------------------------------------------
__global__ __launch_bounds__(256) void decoder_mfma(const short* __restrict__ zh,
                                                    const short* __restrict__ zl,
                                                    float* __restrict__ out) {
  const int p = blockIdx.x;
  int by = (int)((sqrtf(8.f * (float)p + 1.f) - 1.f) * 0.5f);
  while ((by + 1) * (by + 2) / 2 <= p) ++by;
  while (by * (by + 1) / 2 > p) --by;
  const int bx = p - by * (by + 1) / 2;  // bx <= by
  const int i0 = by * 128, j0 = bx * 128;
  const int w = threadIdx.x >> 6, l = threadIdx.x & 63;
  const int lr = l & 15;
  const int koff = (l >> 4) * 8;

  // A fragments: rows i0 + w*32 + rt*16 + lr, k = s*32 + koff + [0..7]
  bf16x8 Ah[2][2], Al[2][2];
  const int arow = i0 + w * 32 + lr;
#pragma unroll
  for (int rt = 0; rt < 2; ++rt)
#pragma unroll
    for (int s = 0; s < 2; ++s) {
      const size_t off = (size_t)(arow + rt * 16) * KP + s * 32 + koff;
      Ah[rt][s] = *(const bf16x8*)(zh + off);
      Al[rt][s] = *(const bf16x8*)(zl + off);
    }

#pragma unroll
  for (int ct = 0; ct < 8; ++ct) {
    const size_t boff = (size_t)(j0 + ct * 16 + lr) * KP + koff;
    const bf16x8 Bh0 = *(const bf16x8*)(zh + boff);
    const bf16x8 Bh1 = *(const bf16x8*)(zh + boff + 32);
    const bf16x8 Bl0 = *(const bf16x8*)(zl + boff);
    const bf16x8 Bl1 = *(const bf16x8*)(zl + boff + 32);
#pragma unroll
    for (int rt = 0; rt < 2; ++rt) {
      f32x4 c = {0.f, 0.f, 0.f, 0.f};
      c = __builtin_amdgcn_mfma_f32_16x16x32_bf16(Ah[rt][0], Bh0, c, 0, 0, 0);
      c = __builtin_amdgcn_mfma_f32_16x16x32_bf16(Ah[rt][1], Bh1, c, 0, 0, 0);
      c = __builtin_amdgcn_mfma_f32_16x16x32_bf16(Ah[rt][0], Bl0, c, 0, 0, 0);
      c = __builtin_amdgcn_mfma_f32_16x16x32_bf16(Ah[rt][1], Bl1, c, 0, 0, 0);
      c = __builtin_amdgcn_mfma_f32_16x16x32_bf16(Al[rt][0], Bh0, c, 0, 0, 0);
      c = __builtin_amdgcn_mfma_f32_16x16x32_bf16(Al[rt][1], Bh1, c, 0, 0, 0);

      float o[4];
#pragma unroll
      for (int j = 0; j < 4; ++j) o[j] = 1.f / (1.f + __expf(-c[j]));

      const int gi0 = i0 + w * 32 + rt * 16 + (l >> 4) * 4;
      const int gj = j0 + ct * 16 + lr;
      if (gj < N_NODES) {
#pragma unroll
        for (int j = 0; j < 4; ++j) {
          const int gi = gi0 + j;
          if (gi < N_NODES) out[(size_t)gi * N_NODES + gj] = o[j];
        }
        if (bx < by) {  // mirror: row gj, cols gi0..gi0+3 (contiguous float4)
          float* dstp = out + (size_t)gj * N_NODES + gi0;
          if (gi0 + 3 < N_NODES) {
            *(float4*)dstp = make_float4(o[0], o[1], o[2], o[3]);
          } else {
#pragma unroll
            for (int j = 0; j < 4; ++j)
              if (gi0 + j < N_NODES) dstp[j] = o[j];
          }
        }
      }
    }
  }
}

// ---------------------------------------------------------------------------
extern "C" void kernel_launch(void* const* d_in, const int* in_sizes, int n_in,
                              void* d_out, int out_size, void* d_ws, size_t ws_size,
                              hipStream_t stream) {
  const float* x     = (const float*)d_in[0];
  const int*   ei    = (const int*)d_in[1];
  const float* W1    = (const float*)d_in[2];
  const float* asrc1 = (const float*)d_in[3];
  const float* adst1 = (const float*)d_in[4];
  const float* b1    = (const float*)d_in[5];
  const float* W2    = (const float*)d_in[6];
  const float* asrc2 = (const float*)d_in[7];
  const float* adst2 = (const float*)d_in[8];
  const float* b2    = (const float*)d_in[9];
  float* out = (float*)d_out;

  // workspace layout (all 16B-aligned)
  float* wsp  = (float*)d_ws;
  float* h1   = wsp;             // N*50
  float* out1 = h1 + 600000;     // N*50
  float* h2   = out1 + 600000;   // N*40
  float* z    = h2 + 480000;     // N*40
  float* as_  = z + 480000;      // N
  float* ad_  = as_ + 12000;     // N
  int* deg  = (int*)(ad_ + 12000);  // N
  int* fill = deg + 12000;          // N
  int* rowp = fill + 12000;         // N+1
  int* esrc = rowp + 12001;         // E+N (396000) -> pad to 396004
  short* zh = (short*)(esrc + 396004);  // NPAD*KP shorts
  short* zl = zh + NPAD * KP;

  const int* src = ei;
  const int* dst = ei + N_EDGES;

  hipMemsetAsync(deg, 0, 2 * N_NODES * sizeof(int), stream);  // deg + fill

  const int eb = (N_EDGES + N_NODES + 255) / 256;
  histo_kernel<<<eb, 256, 0, stream>>>(dst, deg);
  scan_kernel<<<1, 1024, 0, stream>>>(deg, rowp);
  scatter_kernel<<<eb, 256, 0, stream>>>(src, dst, rowp, fill, esrc);

  const int nb = (N_NODES + 255) / 256;
  node_linear<40, 50><<<nb, 256, 0, stream>>>(x, W1, asrc1, adst1, h1, as_, ad_);
  gat_aggregate<50><<<3000, 256, 0, stream>>>(rowp, esrc, h1, as_, ad_, b1, out1);
  node_linear<50, 40><<<nb, 256, 0, stream>>>(out1, W2, asrc2, adst2, h2, as_, ad_);
  gat_aggregate<40><<<3000, 256, 0, stream>>>(rowp, esrc, h2, as_, ad_, b2, z);

  split_bf16<<<(NPAD * KP + 255) / 256, 256, 0, stream>>>(z, zh, zl);

  const int tri = (94 * 95) / 2;  // 4465 lower-triangle tiles
  decoder_mfma<<<tri, 256, 0, stream>>>(zh, zl, out);
}